// Round 14
// baseline (252.943 us; speedup 1.0000x reference)
//
#include <hip/hip_runtime.h>
#include <hip/hip_bf16.h>

#define B_  8
#define T_  2048
#define C_  1024
#define H_  128

using f32x4  = __attribute__((ext_vector_type(4))) float;
using bf16x8 = __attribute__((ext_vector_type(8))) short;

__device__ __forceinline__ unsigned short f2bf(float f) {
    union { float f; unsigned u; } v; v.f = f;
    unsigned r = v.u + 0x7FFFu + ((v.u >> 16) & 1u);   // RNE
    return (unsigned short)(r >> 16);
}

// counted barrier: LDS visibility only (lgkm); register-staged global loads
// stay in flight across it (their waits are register-dependency waits at use).
#define BAR() do { asm volatile("s_waitcnt lgkmcnt(0)" ::: "memory"); \
                   __builtin_amdgcn_s_barrier(); } while (0)

// DPP cross-lane reduce within 16-lane rows (VALU-speed)
template<int C>
__device__ __forceinline__ float dppf(float v) {
    return __int_as_float(__builtin_amdgcn_update_dpp(0, __float_as_int(v), C, 0xF, 0xF, true));
}
#define DPPRED_MAX(v) { v = fmaxf(v, dppf<0xB1>(v)); v = fmaxf(v, dppf<0x4E>(v)); \
                        v = fmaxf(v, dppf<0x141>(v)); v = fmaxf(v, dppf<0x140>(v)); }
#define DPPRED_SUM(v) { v = v + dppf<0xB1>(v); v = v + dppf<0x4E>(v); \
                        v = v + dppf<0x141>(v); v = v + dppf<0x140>(v); }

// ---------------------------------------------------------------------------
// W{q,k,v} fp32 [1024][128] -> Wt K-TILED bf16: Wt[k>>5][col][k&31]
// (each 384x32 B-tile = contiguous 24 KB stream). Wq pre-scaled 1/32.
// ---------------------------------------------------------------------------
__global__ void wconv_kernel(const float* __restrict__ Wq,
                             const float* __restrict__ Wk,
                             const float* __restrict__ Wv,
                             unsigned short* __restrict__ Wt) {
    int id  = blockIdx.x * 256 + threadIdx.x;
    int col = id % 384;
    int k   = id / 384;
    const float* W = (col < 128) ? Wq : ((col < 256) ? Wk : Wv);
    float v = W[k * H_ + (col & 127)];
    if (col < 128) v *= 0.03125f;   // fold C^-0.5 into Wq (exact pow2)
    Wt[(size_t)(k >> 5) * 12288 + col * 32 + (k & 31)] = f2bf(v);
}

// ---------------------------------------------------------------------------
// Fused projection GEMM — R8 geometry + 2-deep REGISTER prefetch + counted
// (lgkm-only) barriers. Grid 512 x 256 thr (4 waves; wave = 32r x 96c,
// acc[2][6]). BK=32, 32 steps. Per step: write LDS from regs loaded 2 steps
// ago (global latency fully covered, nothing drained at the barrier).
// ---------------------------------------------------------------------------
__launch_bounds__(256, 2)
__global__ void gemm_kernel(const float* __restrict__ x,
                            const unsigned short* __restrict__ Wt,
                            unsigned short* __restrict__ qb,
                            unsigned short* __restrict__ kb,
                            unsigned short* __restrict__ vT) {
    __shared__ unsigned short Bs[2][12288];    // [col][k32]
    __shared__ unsigned short As[2][32][32];   // [row][k32]

    const int tid  = threadIdx.x;
    const int wave = tid >> 6;
    const int lane = tid & 63;
    const int lo = lane & 15, hi = lane >> 4;
    const int row0  = blockIdx.x * 32;
    const int col0w = wave * 96;

    const int srow = tid >> 3;                 // A staging: row 0..31
    const int sk4  = (tid & 7) * 4;            // A staging: 4 fp32
    const float* xsrc = x + (size_t)(row0 + srow) * C_ + sk4;
    const unsigned short* bsrc = Wt + tid * 8;

    f32x4 acc[2][6];
    #pragma unroll
    for (int rt = 0; rt < 2; ++rt)
        #pragma unroll
        for (int ct = 0; ct < 6; ++ct)
            acc[rt][ct] = f32x4{0.f, 0.f, 0.f, 0.f};

    // prologue: stage step 0 directly; prefetch steps 1,2 into registers
    {
        #pragma unroll
        for (int j = 0; j < 6; ++j)
            *(uint4*)&Bs[0][tid * 8 + j * 2048] = *(const uint4*)(bsrc + j * 2048);
        float4 f = *(const float4*)(xsrc);
        unsigned a0 = f2bf(f.x) | ((unsigned)f2bf(f.y) << 16);
        unsigned a1 = f2bf(f.z) | ((unsigned)f2bf(f.w) << 16);
        *(uint2*)&As[0][srow][sk4] = uint2{a0, a1};
    }
    uint4 brA[6], brB[6];
    float4 hA, hB;
    #pragma unroll
    for (int j = 0; j < 6; ++j)
        brA[j] = *(const uint4*)(bsrc + 12288 + j * 2048);
    hA = *(const float4*)(xsrc + 32);
    #pragma unroll
    for (int j = 0; j < 6; ++j)
        brB[j] = *(const uint4*)(bsrc + 2 * 12288 + j * 2048);
    hB = *(const float4*)(xsrc + 64);
    BAR();

    for (int k = 0; k < 32; ++k) {
        const int cur = k & 1, nxt = cur ^ 1;

        // fragments from LDS
        bf16x8 af[2], bfr[6];
        #pragma unroll
        for (int rt = 0; rt < 2; ++rt)
            af[rt] = *(const bf16x8*)&As[cur][rt * 16 + lo][hi * 8];
        #pragma unroll
        for (int ct = 0; ct < 6; ++ct)
            bfr[ct] = *(const bf16x8*)&Bs[cur][(col0w + ct * 16 + lo) * 32 + hi * 8];

        #pragma unroll
        for (int ct = 0; ct < 6; ++ct)
            #pragma unroll
            for (int rt = 0; rt < 2; ++rt)
                acc[rt][ct] = __builtin_amdgcn_mfma_f32_16x16x32_bf16(af[rt], bfr[ct], acc[rt][ct], 0, 0, 0);

        // write step k+1 buffers from regs loaded 2 steps ago (latency covered)
        if (k < 31) {
            #pragma unroll
            for (int j = 0; j < 6; ++j)
                *(uint4*)&Bs[nxt][tid * 8 + j * 2048] = brA[j];
            unsigned a0 = f2bf(hA.x) | ((unsigned)f2bf(hA.y) << 16);
            unsigned a1 = f2bf(hA.z) | ((unsigned)f2bf(hA.w) << 16);
            *(uint2*)&As[nxt][srow][sk4] = uint2{a0, a1};
        }

        // shift pipeline and issue loads for step k+3 (clamped)
        #pragma unroll
        for (int j = 0; j < 6; ++j) brA[j] = brB[j];
        hA = hB;
        {
            const int kn = (k + 3 < 31) ? k + 3 : 31;
            const unsigned short* g = bsrc + (size_t)kn * 12288;
            #pragma unroll
            for (int j = 0; j < 6; ++j)
                brB[j] = *(const uint4*)(g + j * 2048);
            hB = *(const float4*)(xsrc + kn * 32);
        }

        BAR();   // lgkm-only: in-flight global loads cross the barrier
    }

    // epilogue
    #pragma unroll
    for (int ct = 0; ct < 6; ++ct) {
        int col = col0w + ct * 16 + lo;
        int head = col >> 7;
        int h = col & 127;
        #pragma unroll
        for (int rt = 0; rt < 2; ++rt) {
            #pragma unroll
            for (int r = 0; r < 4; ++r) {
                int rg = row0 + rt * 16 + 4 * hi + r;
                unsigned short val = f2bf(acc[rt][ct][r]);
                if (head == 0)      qb[(size_t)rg * H_ + h] = val;
                else if (head == 1) kb[(size_t)rg * H_ + h] = val;
                else {
                    int b = rg >> 11, t = rg & (T_ - 1);
                    vT[((size_t)b * H_ + h) * T_ + t] = val;
                }
            }
        }
    }
}

// ---------------------------------------------------------------------------
// Flash pass 1 (R8 form, barriers -> lgkm-only BAR). Block = 8 waves (512 thr);
// QBLK=256; chunk = 256 kv = 4 x KV64 tiles. Grid 512, empties exit.
// ---------------------------------------------------------------------------
__launch_bounds__(512, 2)
__global__ void attn1_kernel(const unsigned short* __restrict__ qb,
                             const unsigned short* __restrict__ kb,
                             const unsigned short* __restrict__ vT,
                             float* __restrict__ Opart,
                             float* __restrict__ MLpart) {
    __shared__ unsigned short Ks[64 * 128];   // [kv][k], 16B chunks XOR-swizzled
    __shared__ unsigned short Vs[128 * 64];   // [h][kv], swizzled
    __shared__ unsigned short Ps[8][16][72];  // per-wave P transpose (2-pass)

    const int tid  = threadIdx.x;
    const int wave = tid >> 6;
    const int lane = tid & 63;
    const int lo = lane & 15, hi = lane >> 4;

    const int bid   = blockIdx.x;
    const int b     = bid & 7;
    const int chunk = (bid >> 3) & 7;
    const int qt    = 7 - (bid >> 6);
    if (chunk > qt) return;

    const int kv_begin = chunk << 8;
    const size_t bT = (size_t)b * T_;
    const int qrow0 = (qt << 8) + wave * 32;

    const int krow = tid >> 3, kcol = (tid & 7) * 2;
    const int vrow = tid >> 2, vcol = (tid & 3) * 2;
    const unsigned short* kgsrc = kb + (bT + krow) * H_ + kcol * 8;
    const unsigned short* vgsrc = vT + ((size_t)b * H_ + vrow) * T_ + vcol * 8;
    unsigned short* kdst0 = &Ks[krow * 128 + ((kcol ^ (krow & 7)) * 8)];
    unsigned short* kdst1 = &Ks[krow * 128 + (((kcol + 1) ^ (krow & 7)) * 8)];
    unsigned short* vdst0 = &Vs[vrow * 64 + ((vcol ^ (vrow & 7)) * 8)];
    unsigned short* vdst1 = &Vs[vrow * 64 + (((vcol + 1) ^ (vrow & 7)) * 8)];

    bf16x8 qf[2][4];
    #pragma unroll
    for (int q2 = 0; q2 < 2; ++q2)
        #pragma unroll
        for (int kc = 0; kc < 4; ++kc)
            qf[q2][kc] = *(const bf16x8*)(qb + (bT + qrow0 + 16 * q2 + lo) * H_ + kc * 32 + 8 * hi);

    float m[2][4], l[2][4];
    f32x4 o[2][8];
    #pragma unroll
    for (int q2 = 0; q2 < 2; ++q2)
        #pragma unroll
        for (int r = 0; r < 4; ++r) { m[q2][r] = -1e30f; l[q2][r] = 0.f; }
    #pragma unroll
    for (int q2 = 0; q2 < 2; ++q2)
        #pragma unroll
        for (int ct = 0; ct < 8; ++ct) o[q2][ct] = f32x4{0.f, 0.f, 0.f, 0.f};

    uint4 kr0 = *(const uint4*)(kgsrc + (size_t)kv_begin * H_);
    uint4 kr1 = *(const uint4*)(kgsrc + (size_t)kv_begin * H_ + 8);
    uint4 vr0 = *(const uint4*)(vgsrc + kv_begin);
    uint4 vr1 = *(const uint4*)(vgsrc + kv_begin + 8);

    for (int t = 0; t < 4; ++t) {
        const int kv0 = kv_begin + t * 64;
        BAR();                                 // all reads of prev tile done
        *(uint4*)kdst0 = kr0;
        *(uint4*)kdst1 = kr1;
        *(uint4*)vdst0 = vr0;
        *(uint4*)vdst1 = vr1;
        BAR();                                 // tile staged (lgkm drained)
        if (t < 3) {                           // issue next-tile loads now
            const int kvn = kv0 + 64;
            kr0 = *(const uint4*)(kgsrc + (size_t)kvn * H_);
            kr1 = *(const uint4*)(kgsrc + (size_t)kvn * H_ + 8);
            vr0 = *(const uint4*)(vgsrc + kvn);
            vr1 = *(const uint4*)(vgsrc + kvn + 8);
        }
        if (kv0 > qrow0 + 31) continue;        // fully masked for this wave

        f32x4 s[2][4];
        #pragma unroll
        for (int q2 = 0; q2 < 2; ++q2)
            #pragma unroll
            for (int ct4 = 0; ct4 < 4; ++ct4) s[q2][ct4] = f32x4{0.f, 0.f, 0.f, 0.f};
        __builtin_amdgcn_s_setprio(1);
        #pragma unroll
        for (int ct4 = 0; ct4 < 4; ++ct4) {
            const int row = ct4 * 16 + lo;
            #pragma unroll
            for (int kc = 0; kc < 4; ++kc) {
                bf16x8 kf = *(const bf16x8*)&Ks[row * 128 + (((kc * 4 + hi) ^ (row & 7)) * 8)];
                s[0][ct4] = __builtin_amdgcn_mfma_f32_16x16x32_bf16(qf[0][kc], kf, s[0][ct4], 0, 0, 0);
                s[1][ct4] = __builtin_amdgcn_mfma_f32_16x16x32_bf16(qf[1][kc], kf, s[1][ct4], 0, 0, 0);
            }
        }
        __builtin_amdgcn_s_setprio(0);

        if (kv0 + 63 >= qrow0) {
            #pragma unroll
            for (int q2 = 0; q2 < 2; ++q2)
                #pragma unroll
                for (int ct4 = 0; ct4 < 4; ++ct4)
                    #pragma unroll
                    for (int r = 0; r < 4; ++r)
                        if (kv0 + ct4 * 16 + lo > qrow0 + 16 * q2 + 4 * hi + r)
                            s[q2][ct4][r] = -1e30f;
        }

        float alpha[2][4];
        #pragma unroll
        for (int q2 = 0; q2 < 2; ++q2) {
            #pragma unroll
            for (int r = 0; r < 4; ++r) {
                float pm = fmaxf(fmaxf(s[q2][0][r], s[q2][1][r]), fmaxf(s[q2][2][r], s[q2][3][r]));
                DPPRED_MAX(pm);
                float mn = fmaxf(m[q2][r], pm);
                alpha[q2][r] = __expf(m[q2][r] - mn);
                m[q2][r] = mn;
                #pragma unroll
                for (int ct4 = 0; ct4 < 4; ++ct4) s[q2][ct4][r] = __expf(s[q2][ct4][r] - mn);
                float rs = (s[q2][0][r] + s[q2][1][r]) + (s[q2][2][r] + s[q2][3][r]);
                DPPRED_SUM(rs);
                l[q2][r] = l[q2][r] * alpha[q2][r] + rs;
            }
        }
        #pragma unroll
        for (int q2 = 0; q2 < 2; ++q2)
            #pragma unroll
            for (int ct = 0; ct < 8; ++ct)
                #pragma unroll
                for (int r = 0; r < 4; ++r) o[q2][ct][r] *= alpha[q2][r];

        bf16x8 pa[2][2];
        #pragma unroll
        for (int q2 = 0; q2 < 2; ++q2) {
            #pragma unroll
            for (int ct4 = 0; ct4 < 4; ++ct4)
                #pragma unroll
                for (int r = 0; r < 4; ++r)
                    Ps[wave][4 * hi + r][ct4 * 16 + lo] = f2bf(s[q2][ct4][r]);
            pa[q2][0] = *(const bf16x8*)&Ps[wave][lo][8 * hi];
            pa[q2][1] = *(const bf16x8*)&Ps[wave][lo][32 + 8 * hi];
        }

        __builtin_amdgcn_s_setprio(1);
        #pragma unroll
        for (int ct = 0; ct < 8; ++ct) {
            const int row = ct * 16 + lo;
            #pragma unroll
            for (int half = 0; half < 2; ++half) {
                bf16x8 vf = *(const bf16x8*)&Vs[row * 64 + (((half * 4 + hi) ^ (row & 7)) * 8)];
                o[0][ct] = __builtin_amdgcn_mfma_f32_16x16x32_bf16(pa[0][half], vf, o[0][ct], 0, 0, 0);
                o[1][ct] = __builtin_amdgcn_mfma_f32_16x16x32_bf16(pa[1][half], vf, o[1][ct], 0, 0, 0);
            }
        }
        __builtin_amdgcn_s_setprio(0);
    }

    const int slot = b * 36 + ((qt * (qt + 1)) >> 1) + chunk;
    float* op = Opart + (size_t)slot * 32768 + (size_t)(wave * 32) * 128;
    #pragma unroll
    for (int q2 = 0; q2 < 2; ++q2)
        #pragma unroll
        for (int ct = 0; ct < 8; ++ct)
            #pragma unroll
            for (int r = 0; r < 4; ++r)
                op[(16 * q2 + 4 * hi + r) * 128 + ct * 16 + lo] = o[q2][ct][r];
    if (lo == 0) {
        #pragma unroll
        for (int q2 = 0; q2 < 2; ++q2)
            #pragma unroll
            for (int r = 0; r < 4; ++r) {
                int base = slot * 512 + (wave * 32 + 16 * q2 + 4 * hi + r) * 2;
                MLpart[base]     = m[q2][r];
                MLpart[base + 1] = l[q2][r];
            }
    }
}

// ---------------------------------------------------------------------------
// Flash pass 2: merge <= 8 chunk partials. 512 blocks x 128 thr.
// ---------------------------------------------------------------------------
__launch_bounds__(128)
__global__ void attn2_kernel(const float* __restrict__ Opart,
                             const float* __restrict__ MLpart,
                             float* __restrict__ out) {
    const int bid = blockIdx.x;
    const int b   = bid & 7;
    const int qt  = (bid >> 3) & 7;
    const int sub = bid >> 6;              // 0..7
    const int nch = qt + 1;
    const int slot0 = b * 36 + ((qt * (qt + 1)) >> 1);

    const int tid  = threadIdx.x;
    const int row  = tid >> 2;             // 0..31
    const int h0   = (tid & 3) * 32;
    const int srow = sub * 32 + row;       // row within slot

    float M = -1e30f;
    for (int c = 0; c < nch; ++c)
        M = fmaxf(M, MLpart[(slot0 + c) * 512 + srow * 2]);
    float L = 0.f;
    for (int c = 0; c < nch; ++c) {
        float mc = MLpart[(slot0 + c) * 512 + srow * 2];
        float lc = MLpart[(slot0 + c) * 512 + srow * 2 + 1];
        L += lc * __expf(mc - M);
    }

    float4 acc[8];
    #pragma unroll
    for (int j = 0; j < 8; ++j) acc[j] = float4{0.f, 0.f, 0.f, 0.f};
    for (int c = 0; c < nch; ++c) {
        float wc = __expf(MLpart[(slot0 + c) * 512 + srow * 2] - M);
        const float4* src = (const float4*)(Opart + (size_t)(slot0 + c) * 32768 + (size_t)srow * 128 + h0);
        #pragma unroll
        for (int j = 0; j < 8; ++j) {
            float4 v = src[j];
            acc[j].x += wc * v.x; acc[j].y += wc * v.y;
            acc[j].z += wc * v.z; acc[j].w += wc * v.w;
        }
    }
    float inv = 1.f / L;
    float4* dst = (float4*)(out + ((size_t)b * T_ + qt * 256 + srow) * H_ + h0);
    #pragma unroll
    for (int j = 0; j < 8; ++j) {
        float4 v = acc[j];
        dst[j] = float4{v.x * inv, v.y * inv, v.z * inv, v.w * inv};
    }
}

extern "C" void kernel_launch(void* const* d_in, const int* in_sizes, int n_in,
                              void* d_out, int out_size, void* d_ws, size_t ws_size,
                              hipStream_t stream) {
    const float* x  = (const float*)d_in[0];
    const float* Wq = (const float*)d_in[1];
    const float* Wk = (const float*)d_in[2];
    const float* Wv = (const float*)d_in[3];
    float* out = (float*)d_out;

    char* ws = (char*)d_ws;
    unsigned short* Wt  = (unsigned short*)ws;                          // 0.75 MB
    unsigned short* qbf = (unsigned short*)(ws + (size_t)384 * 1024 * 2);
    unsigned short* kbf = qbf + (size_t)B_ * T_ * H_;
    unsigned short* vTf = kbf + (size_t)B_ * T_ * H_;
    float* Opart  = (float*)(vTf + (size_t)B_ * T_ * H_);               // 36 MB
    float* MLpart = (float*)((char*)Opart + (size_t)288 * 32768 * 4);   // 0.56 MB

    wconv_kernel<<<(384 * 1024) / 256, 256, 0, stream>>>(Wq, Wk, Wv, Wt);
    gemm_kernel<<<B_ * T_ / 32, 256, 0, stream>>>(x, Wt, qbf, kbf, vTf);
    attn1_kernel<<<512, 512, 0, stream>>>(qbf, kbf, vTf, Opart, MLpart);
    attn2_kernel<<<512, 128, 0, stream>>>(Opart, MLpart, out);
}

// Round 15
// 87.536 us; speedup vs baseline: 2.8896x; 2.8896x over previous
//
#include <hip/hip_runtime.h>
#include <hip/hip_bf16.h>

#define B_  8
#define T_  2048
#define C_  1024
#define H_  128

using f32x4  = __attribute__((ext_vector_type(4))) float;
using f32x16 = __attribute__((ext_vector_type(16))) float;
using bf16x8 = __attribute__((ext_vector_type(8))) short;

__device__ __forceinline__ unsigned short f2bf(float f) {
    union { float f; unsigned u; } v; v.f = f;
    unsigned r = v.u + 0x7FFFu + ((v.u >> 16) & 1u);   // RNE
    return (unsigned short)(r >> 16);
}

// lgkm-only barrier: LDS visibility; register-staged global loads stay in flight
#define BAR() do { asm volatile("s_waitcnt lgkmcnt(0)" ::: "memory"); \
                   __builtin_amdgcn_s_barrier(); } while (0)

// DPP cross-lane reduce within 16-lane rows (VALU-speed)
template<int C>
__device__ __forceinline__ float dppf(float v) {
    return __int_as_float(__builtin_amdgcn_update_dpp(0, __float_as_int(v), C, 0xF, 0xF, true));
}
#define DPPRED_MAX(v) { v = fmaxf(v, dppf<0xB1>(v)); v = fmaxf(v, dppf<0x4E>(v)); \
                        v = fmaxf(v, dppf<0x141>(v)); v = fmaxf(v, dppf<0x140>(v)); }
#define DPPRED_SUM(v) { v = v + dppf<0xB1>(v); v = v + dppf<0x4E>(v); \
                        v = v + dppf<0x141>(v); v = v + dppf<0x140>(v); }

// ---------------------------------------------------------------------------
// W{q,k,v} fp32 [1024][128] -> Wt K-TILED bf16: Wt[k>>5][col][k&31]
// (each 384x32 B-tile = contiguous 24 KB stream). Wq pre-scaled 1/32.
// ---------------------------------------------------------------------------
__global__ void wconv_kernel(const float* __restrict__ Wq,
                             const float* __restrict__ Wk,
                             const float* __restrict__ Wv,
                             unsigned short* __restrict__ Wt) {
    int id  = blockIdx.x * 256 + threadIdx.x;
    int col = id % 384;
    int k   = id / 384;
    const float* W = (col < 128) ? Wq : ((col < 256) ? Wk : Wv);
    float v = W[k * H_ + (col & 127)];
    if (col < 128) v *= 0.03125f;   // fold C^-0.5 into Wq (exact pow2)
    Wt[(size_t)(k >> 5) * 12288 + col * 32 + (k & 31)] = f2bf(v);
}

// ---------------------------------------------------------------------------
// Fused projection GEMM — 32x32x16 MFMA, BM=64. Grid 256 x 512 thr (8 waves:
// 2 row-groups x 4 col-panels; wave = 32r x 96c, acc = 3 x f32x16). BK=32,
// 32 steps, dbuf, 1 barrier/step (R8-proven skeleton).
// Per wave-step: 8 ds_read_b128 + 6 MFMA (2x FLOP/instr vs 16x16) — LDS-ops
// and L2 bytes per FLOP cut ~2x. B staged 1-deep from L2 (24KB stream);
// x (HBM) prefetched 3-deep in regs. LDS padded [*][36]: <=2-way, free.
// ---------------------------------------------------------------------------
__launch_bounds__(512, 2)
__global__ void gemm_kernel(const float* __restrict__ x,
                            const unsigned short* __restrict__ Wt,
                            unsigned short* __restrict__ qb,
                            unsigned short* __restrict__ kb,
                            unsigned short* __restrict__ vT) {
    __shared__ unsigned short Bs[2][13824];   // [384 col][36], pad 32->36
    __shared__ unsigned short As[2][2304];    // [64 row][36]

    const int tid  = threadIdx.x;
    const int wave = tid >> 6;
    const int lane = tid & 63;
    const int r32 = lane & 31, hi32 = lane >> 5;
    const int row0 = blockIdx.x * 64;
    const int wrow  = (wave >> 2) * 32;       // wave's row group within tile
    const int wcol0 = (wave & 3) * 96;        // wave's col panel

    // A staging: thread -> (row = tid>>3, 4 fp32 at (tid&7)*4)
    const int arow = tid >> 3;
    const int ak4  = (tid & 7) * 4;
    const float* xsrc = x + (size_t)(row0 + arow) * C_ + ak4;

    // B staging: 3 x 16B chunks; chunk = tid + j*512 -> col=chunk>>2, sub=chunk&3
    const unsigned short* bsrc = Wt + (size_t)tid * 8;

    f32x16 acc[3];
    #pragma unroll
    for (int ct = 0; ct < 3; ++ct)
        #pragma unroll
        for (int e = 0; e < 16; ++e) acc[ct][e] = 0.f;

    // prologue: stage step 0 directly; x(1), x(2) into regs
    {
        #pragma unroll
        for (int j = 0; j < 3; ++j) {
            const int chunk = tid + j * 512;
            *(uint4*)&Bs[0][(chunk >> 2) * 36 + (chunk & 3) * 8] =
                *(const uint4*)(bsrc + j * 4096);
        }
        float4 f = *(const float4*)(xsrc);
        unsigned a0 = f2bf(f.x) | ((unsigned)f2bf(f.y) << 16);
        unsigned a1 = f2bf(f.z) | ((unsigned)f2bf(f.w) << 16);
        *(uint2*)&As[0][arow * 36 + ak4] = uint2{a0, a1};
    }
    float4 hA = *(const float4*)(xsrc + 32);
    float4 hB = *(const float4*)(xsrc + 64);
    BAR();

    for (int k = 0; k < 32; ++k) {
        const int cur = k & 1, nxt = cur ^ 1;

        // top: issue B(k+1) (L2) and x(k+3) (HBM, 3-deep) loads
        uint4 br[3];
        float4 xf;
        if (k < 31) {
            const unsigned short* g = bsrc + (size_t)(k + 1) * 12288;
            #pragma unroll
            for (int j = 0; j < 3; ++j) br[j] = *(const uint4*)(g + j * 4096);
        }
        {
            const int kn = (k + 3 < 31) ? k + 3 : 31;
            xf = *(const float4*)(xsrc + kn * 32);
        }

        // MFMA: 2 k-halves x 3 col-tiles of 32
        #pragma unroll
        for (int kh = 0; kh < 2; ++kh) {
            const int kofs = kh * 16 + 8 * hi32;
            bf16x8 af = *(const bf16x8*)&As[cur][(wrow + r32) * 36 + kofs];
            #pragma unroll
            for (int ct = 0; ct < 3; ++ct) {
                bf16x8 bf = *(const bf16x8*)&Bs[cur][(wcol0 + ct * 32 + r32) * 36 + kofs];
                acc[ct] = __builtin_amdgcn_mfma_f32_32x32x16_bf16(af, bf, acc[ct], 0, 0, 0);
            }
        }

        // write step k+1 buffers
        if (k < 31) {
            #pragma unroll
            for (int j = 0; j < 3; ++j) {
                const int chunk = tid + j * 512;
                *(uint4*)&Bs[nxt][(chunk >> 2) * 36 + (chunk & 3) * 8] = br[j];
            }
            unsigned a0 = f2bf(hA.x) | ((unsigned)f2bf(hA.y) << 16);
            unsigned a1 = f2bf(hA.z) | ((unsigned)f2bf(hA.w) << 16);
            *(uint2*)&As[nxt][arow * 36 + ak4] = uint2{a0, a1};
        }
        BAR();
        hA = hB; hB = xf;
    }

    // epilogue: C/D layout col = lane&31, row = (reg&3) + 8*(reg>>2) + 4*(lane>>5)
    #pragma unroll
    for (int ct = 0; ct < 3; ++ct) {
        int col = wcol0 + ct * 32 + r32;
        int head = col >> 7;
        int h = col & 127;
        #pragma unroll
        for (int reg = 0; reg < 16; ++reg) {
            int rg = row0 + wrow + (reg & 3) + 8 * (reg >> 2) + 4 * hi32;
            unsigned short val = f2bf(acc[ct][reg]);
            if (head == 0)      qb[(size_t)rg * H_ + h] = val;
            else if (head == 1) kb[(size_t)rg * H_ + h] = val;
            else {
                int b = rg >> 11, t = rg & (T_ - 1);
                vT[((size_t)b * H_ + h) * T_ + t] = val;
            }
        }
    }
}

// ---------------------------------------------------------------------------
// Flash pass 1 (R8 form + lgkm-only BAR; passed in R14). Block = 8 waves;
// QBLK=256; chunk = 256 kv = 4 x KV64 tiles. Grid 512, empties exit.
// ---------------------------------------------------------------------------
__launch_bounds__(512, 2)
__global__ void attn1_kernel(const unsigned short* __restrict__ qb,
                             const unsigned short* __restrict__ kb,
                             const unsigned short* __restrict__ vT,
                             float* __restrict__ Opart,
                             float* __restrict__ MLpart) {
    __shared__ unsigned short Ks[64 * 128];   // [kv][k], 16B chunks XOR-swizzled
    __shared__ unsigned short Vs[128 * 64];   // [h][kv], swizzled
    __shared__ unsigned short Ps[8][16][72];  // per-wave P transpose (2-pass)

    const int tid  = threadIdx.x;
    const int wave = tid >> 6;
    const int lane = tid & 63;
    const int lo = lane & 15, hi = lane >> 4;

    const int bid   = blockIdx.x;
    const int b     = bid & 7;
    const int chunk = (bid >> 3) & 7;
    const int qt    = 7 - (bid >> 6);
    if (chunk > qt) return;

    const int kv_begin = chunk << 8;
    const size_t bT = (size_t)b * T_;
    const int qrow0 = (qt << 8) + wave * 32;

    const int krow = tid >> 3, kcol = (tid & 7) * 2;
    const int vrow = tid >> 2, vcol = (tid & 3) * 2;
    const unsigned short* kgsrc = kb + (bT + krow) * H_ + kcol * 8;
    const unsigned short* vgsrc = vT + ((size_t)b * H_ + vrow) * T_ + vcol * 8;
    unsigned short* kdst0 = &Ks[krow * 128 + ((kcol ^ (krow & 7)) * 8)];
    unsigned short* kdst1 = &Ks[krow * 128 + (((kcol + 1) ^ (krow & 7)) * 8)];
    unsigned short* vdst0 = &Vs[vrow * 64 + ((vcol ^ (vrow & 7)) * 8)];
    unsigned short* vdst1 = &Vs[vrow * 64 + (((vcol + 1) ^ (vrow & 7)) * 8)];

    bf16x8 qf[2][4];
    #pragma unroll
    for (int q2 = 0; q2 < 2; ++q2)
        #pragma unroll
        for (int kc = 0; kc < 4; ++kc)
            qf[q2][kc] = *(const bf16x8*)(qb + (bT + qrow0 + 16 * q2 + lo) * H_ + kc * 32 + 8 * hi);

    float m[2][4], l[2][4];
    f32x4 o[2][8];
    #pragma unroll
    for (int q2 = 0; q2 < 2; ++q2)
        #pragma unroll
        for (int r = 0; r < 4; ++r) { m[q2][r] = -1e30f; l[q2][r] = 0.f; }
    #pragma unroll
    for (int q2 = 0; q2 < 2; ++q2)
        #pragma unroll
        for (int ct = 0; ct < 8; ++ct) o[q2][ct] = f32x4{0.f, 0.f, 0.f, 0.f};

    uint4 kr0 = *(const uint4*)(kgsrc + (size_t)kv_begin * H_);
    uint4 kr1 = *(const uint4*)(kgsrc + (size_t)kv_begin * H_ + 8);
    uint4 vr0 = *(const uint4*)(vgsrc + kv_begin);
    uint4 vr1 = *(const uint4*)(vgsrc + kv_begin + 8);

    for (int t = 0; t < 4; ++t) {
        const int kv0 = kv_begin + t * 64;
        BAR();
        *(uint4*)kdst0 = kr0;
        *(uint4*)kdst1 = kr1;
        *(uint4*)vdst0 = vr0;
        *(uint4*)vdst1 = vr1;
        BAR();
        if (t < 3) {
            const int kvn = kv0 + 64;
            kr0 = *(const uint4*)(kgsrc + (size_t)kvn * H_);
            kr1 = *(const uint4*)(kgsrc + (size_t)kvn * H_ + 8);
            vr0 = *(const uint4*)(vgsrc + kvn);
            vr1 = *(const uint4*)(vgsrc + kvn + 8);
        }
        if (kv0 > qrow0 + 31) continue;

        f32x4 s[2][4];
        #pragma unroll
        for (int q2 = 0; q2 < 2; ++q2)
            #pragma unroll
            for (int ct4 = 0; ct4 < 4; ++ct4) s[q2][ct4] = f32x4{0.f, 0.f, 0.f, 0.f};
        __builtin_amdgcn_s_setprio(1);
        #pragma unroll
        for (int ct4 = 0; ct4 < 4; ++ct4) {
            const int row = ct4 * 16 + lo;
            #pragma unroll
            for (int kc = 0; kc < 4; ++kc) {
                bf16x8 kf = *(const bf16x8*)&Ks[row * 128 + (((kc * 4 + hi) ^ (row & 7)) * 8)];
                s[0][ct4] = __builtin_amdgcn_mfma_f32_16x16x32_bf16(qf[0][kc], kf, s[0][ct4], 0, 0, 0);
                s[1][ct4] = __builtin_amdgcn_mfma_f32_16x16x32_bf16(qf[1][kc], kf, s[1][ct4], 0, 0, 0);
            }
        }
        __builtin_amdgcn_s_setprio(0);

        if (kv0 + 63 >= qrow0) {
            #pragma unroll
            for (int q2 = 0; q2 < 2; ++q2)
                #pragma unroll
                for (int ct4 = 0; ct4 < 4; ++ct4)
                    #pragma unroll
                    for (int r = 0; r < 4; ++r)
                        if (kv0 + ct4 * 16 + lo > qrow0 + 16 * q2 + 4 * hi + r)
                            s[q2][ct4][r] = -1e30f;
        }

        float alpha[2][4];
        #pragma unroll
        for (int q2 = 0; q2 < 2; ++q2) {
            #pragma unroll
            for (int r = 0; r < 4; ++r) {
                float pm = fmaxf(fmaxf(s[q2][0][r], s[q2][1][r]), fmaxf(s[q2][2][r], s[q2][3][r]));
                DPPRED_MAX(pm);
                float mn = fmaxf(m[q2][r], pm);
                alpha[q2][r] = __expf(m[q2][r] - mn);
                m[q2][r] = mn;
                #pragma unroll
                for (int ct4 = 0; ct4 < 4; ++ct4) s[q2][ct4][r] = __expf(s[q2][ct4][r] - mn);
                float rs = (s[q2][0][r] + s[q2][1][r]) + (s[q2][2][r] + s[q2][3][r]);
                DPPRED_SUM(rs);
                l[q2][r] = l[q2][r] * alpha[q2][r] + rs;
            }
        }
        #pragma unroll
        for (int q2 = 0; q2 < 2; ++q2)
            #pragma unroll
            for (int ct = 0; ct < 8; ++ct)
                #pragma unroll
                for (int r = 0; r < 4; ++r) o[q2][ct][r] *= alpha[q2][r];

        bf16x8 pa[2][2];
        #pragma unroll
        for (int q2 = 0; q2 < 2; ++q2) {
            #pragma unroll
            for (int ct4 = 0; ct4 < 4; ++ct4)
                #pragma unroll
                for (int r = 0; r < 4; ++r)
                    Ps[wave][4 * hi + r][ct4 * 16 + lo] = f2bf(s[q2][ct4][r]);
            pa[q2][0] = *(const bf16x8*)&Ps[wave][lo][8 * hi];
            pa[q2][1] = *(const bf16x8*)&Ps[wave][lo][32 + 8 * hi];
        }

        __builtin_amdgcn_s_setprio(1);
        #pragma unroll
        for (int ct = 0; ct < 8; ++ct) {
            const int row = ct * 16 + lo;
            #pragma unroll
            for (int half = 0; half < 2; ++half) {
                bf16x8 vf = *(const bf16x8*)&Vs[row * 64 + (((half * 4 + hi) ^ (row & 7)) * 8)];
                o[0][ct] = __builtin_amdgcn_mfma_f32_16x16x32_bf16(pa[0][half], vf, o[0][ct], 0, 0, 0);
                o[1][ct] = __builtin_amdgcn_mfma_f32_16x16x32_bf16(pa[1][half], vf, o[1][ct], 0, 0, 0);
            }
        }
        __builtin_amdgcn_s_setprio(0);
    }

    const int slot = b * 36 + ((qt * (qt + 1)) >> 1) + chunk;
    float* op = Opart + (size_t)slot * 32768 + (size_t)(wave * 32) * 128;
    #pragma unroll
    for (int q2 = 0; q2 < 2; ++q2)
        #pragma unroll
        for (int ct = 0; ct < 8; ++ct)
            #pragma unroll
            for (int r = 0; r < 4; ++r)
                op[(16 * q2 + 4 * hi + r) * 128 + ct * 16 + lo] = o[q2][ct][r];
    if (lo == 0) {
        #pragma unroll
        for (int q2 = 0; q2 < 2; ++q2)
            #pragma unroll
            for (int r = 0; r < 4; ++r) {
                int base = slot * 512 + (wave * 32 + 16 * q2 + 4 * hi + r) * 2;
                MLpart[base]     = m[q2][r];
                MLpart[base + 1] = l[q2][r];
            }
    }
}

// ---------------------------------------------------------------------------
// Flash pass 2: merge <= 8 chunk partials. 512 blocks x 128 thr.
// ---------------------------------------------------------------------------
__launch_bounds__(128)
__global__ void attn2_kernel(const float* __restrict__ Opart,
                             const float* __restrict__ MLpart,
                             float* __restrict__ out) {
    const int bid = blockIdx.x;
    const int b   = bid & 7;
    const int qt  = (bid >> 3) & 7;
    const int sub = bid >> 6;              // 0..7
    const int nch = qt + 1;
    const int slot0 = b * 36 + ((qt * (qt + 1)) >> 1);

    const int tid  = threadIdx.x;
    const int row  = tid >> 2;             // 0..31
    const int h0   = (tid & 3) * 32;
    const int srow = sub * 32 + row;       // row within slot

    float M = -1e30f;
    for (int c = 0; c < nch; ++c)
        M = fmaxf(M, MLpart[(slot0 + c) * 512 + srow * 2]);
    float L = 0.f;
    for (int c = 0; c < nch; ++c) {
        float mc = MLpart[(slot0 + c) * 512 + srow * 2];
        float lc = MLpart[(slot0 + c) * 512 + srow * 2 + 1];
        L += lc * __expf(mc - M);
    }

    float4 acc[8];
    #pragma unroll
    for (int j = 0; j < 8; ++j) acc[j] = float4{0.f, 0.f, 0.f, 0.f};
    for (int c = 0; c < nch; ++c) {
        float wc = __expf(MLpart[(slot0 + c) * 512 + srow * 2] - M);
        const float4* src = (const float4*)(Opart + (size_t)(slot0 + c) * 32768 + (size_t)srow * 128 + h0);
        #pragma unroll
        for (int j = 0; j < 8; ++j) {
            float4 v = src[j];
            acc[j].x += wc * v.x; acc[j].y += wc * v.y;
            acc[j].z += wc * v.z; acc[j].w += wc * v.w;
        }
    }
    float inv = 1.f / L;
    float4* dst = (float4*)(out + ((size_t)b * T_ + qt * 256 + srow) * H_ + h0);
    #pragma unroll
    for (int j = 0; j < 8; ++j) {
        float4 v = acc[j];
        dst[j] = float4{v.x * inv, v.y * inv, v.z * inv, v.w * inv};
    }
}

extern "C" void kernel_launch(void* const* d_in, const int* in_sizes, int n_in,
                              void* d_out, int out_size, void* d_ws, size_t ws_size,
                              hipStream_t stream) {
    const float* x  = (const float*)d_in[0];
    const float* Wq = (const float*)d_in[1];
    const float* Wk = (const float*)d_in[2];
    const float* Wv = (const float*)d_in[3];
    float* out = (float*)d_out;

    char* ws = (char*)d_ws;
    unsigned short* Wt  = (unsigned short*)ws;                          // 0.75 MB
    unsigned short* qbf = (unsigned short*)(ws + (size_t)384 * 1024 * 2);
    unsigned short* kbf = qbf + (size_t)B_ * T_ * H_;
    unsigned short* vTf = kbf + (size_t)B_ * T_ * H_;
    float* Opart  = (float*)(vTf + (size_t)B_ * T_ * H_);               // 36 MB
    float* MLpart = (float*)((char*)Opart + (size_t)288 * 32768 * 4);   // 0.56 MB

    wconv_kernel<<<(384 * 1024) / 256, 256, 0, stream>>>(Wq, Wk, Wv, Wt);
    gemm_kernel<<<B_ * T_ / 64, 512, 0, stream>>>(x, Wt, qbf, kbf, vTf);
    attn1_kernel<<<512, 512, 0, stream>>>(qbf, kbf, vTf, Opart, MLpart);
    attn2_kernel<<<512, 128, 0, stream>>>(Opart, MLpart, out);
}